// Round 5
// baseline (449.016 us; speedup 1.0000x reference)
//
#include <hip/hip_runtime.h>
#include <hip/hip_bf16.h>

#define BB 32
#define NN 256
#define HH 768
#define NHEADS 12
#define DH 64
#define PHDIM 128
#define NVOCAB 35

typedef short bf16x8 __attribute__((ext_vector_type(8)));
typedef float f32x16 __attribute__((ext_vector_type(16)));
typedef float f32x2 __attribute__((ext_vector_type(2)));
typedef unsigned u32x2 __attribute__((ext_vector_type(2)));

#define MFMA32 __builtin_amdgcn_mfma_f32_32x32x16_bf16

// round-to-nearest-even f32 -> bf16 bits
__device__ __forceinline__ unsigned short f2bf(float f) {
    unsigned u = __float_as_uint(f);
    unsigned r = (u + 0x7fffu + ((u >> 16) & 1u)) >> 16;
    return (unsigned short)r;
}

__device__ __forceinline__ unsigned pk2(float a, float b) {
    return (unsigned)f2bf(a) | ((unsigned)f2bf(b) << 16);
}

__device__ __forceinline__ bf16x8 pack8(const float f[8]) {
    bf16x8 r;
#pragma unroll
    for (int e = 0; e < 8; ++e) r[e] = (short)f2bf(f[e]);
    return r;
}

// ---------------------------------------------------------------------------
// Kernel 0a: cast nodes f32 -> bf16
// ---------------------------------------------------------------------------
__global__ __launch_bounds__(256) void k_cast(const float* __restrict__ in,
                                              unsigned short* __restrict__ out) {
    int i = (blockIdx.x * 256 + threadIdx.x) * 4;
    float4 v = *reinterpret_cast<const float4*>(&in[i]);
    ushort4 o;
    o.x = f2bf(v.x); o.y = f2bf(v.y); o.z = f2bf(v.z); o.w = f2bf(v.w);
    *reinterpret_cast<ushort4*>(&out[i]) = o;
}

// ---------------------------------------------------------------------------
// Kernel 0b: transpose+cast weights -> Wt[z][col][k] bf16 (z: Wq,Wk,Wv,Wo)
// ---------------------------------------------------------------------------
__global__ __launch_bounds__(256) void k_prep_w(
        const float* __restrict__ Wq, const float* __restrict__ Wk,
        const float* __restrict__ Wv, const float* __restrict__ Wo,
        unsigned short* __restrict__ Wt) {
    __shared__ unsigned short tile[64][72];
    int z = blockIdx.z;
    const float* W = (z == 0) ? Wq : (z == 1) ? Wk : (z == 2) ? Wv : Wo;
    unsigned short* out = Wt + (size_t)z * HH * HH;
    int k0 = blockIdx.x * 64, c0 = blockIdx.y * 64;
    int tid = threadIdx.x;
#pragma unroll
    for (int l = 0; l < 16; ++l) {
        int e = tid + l * 256;
        int r = e >> 6, c = e & 63;
        tile[c][r] = f2bf(W[(size_t)(k0 + r) * HH + c0 + c]);
    }
    __syncthreads();
#pragma unroll
    for (int l = 0; l < 2; ++l) {
        int e = tid + l * 256;
        int c = e >> 3, ch = e & 7;
        *reinterpret_cast<bf16x8*>(&out[(size_t)(c0 + c) * HH + k0 + ch * 8]) =
            *reinterpret_cast<const bf16x8*>(&tile[c][ch * 8]);
    }
}

// ---------------------------------------------------------------------------
// Kernel 1: LN(pos_table) @ Wsk/Wsv -> bf16 vocab tables
// ---------------------------------------------------------------------------
__global__ void k_vocab(const float* __restrict__ pos_table,
                        const float* __restrict__ g_path, const float* __restrict__ b_path,
                        const float* __restrict__ Wsk, const float* __restrict__ bsk,
                        const float* __restrict__ Wsv, const float* __restrict__ bsv,
                        unsigned short* __restrict__ skv_bf, unsigned short* __restrict__ svv_t_bf) {
    int v = blockIdx.x;
    int t = threadIdx.x;  // 128
    if (v >= NVOCAB) {
        if (t < 64) skv_bf[v * 64 + t] = 0;
        else if (v < 48) svv_t_bf[(t - 64) * 48 + v] = 0;
        return;
    }
    __shared__ float x[PHDIM];
    __shared__ float red[PHDIM];
    float xv = pos_table[v * PHDIM + t];
    red[t] = xv;
    __syncthreads();
    for (int s = 64; s > 0; s >>= 1) { if (t < s) red[t] += red[t + s]; __syncthreads(); }
    float mean = red[0] / PHDIM;
    __syncthreads();
    float c = xv - mean;
    red[t] = c * c;
    __syncthreads();
    for (int s = 64; s > 0; s >>= 1) { if (t < s) red[t] += red[t + s]; __syncthreads(); }
    float var = red[0] / PHDIM;
    float ln = (xv - mean) * rsqrtf(var + 1e-5f) * g_path[t] + b_path[t];
    __syncthreads();
    x[t] = ln;
    __syncthreads();
    if (t < 64) {
        float acc = bsk[t];
        for (int p = 0; p < PHDIM; ++p) acc += x[p] * Wsk[p * DH + t];
        skv_bf[v * 64 + t] = f2bf(acc);
    } else {
        int d = t - 64;
        float acc = bsv[d];
        for (int p = 0; p < PHDIM; ++p) acc += x[p] * Wsv[p * DH + d];
        svv_t_bf[d * 48 + v] = f2bf(acc);
    }
}

// ---------------------------------------------------------------------------
// Kernel 2: QKV MFMA GEMM -> bf16 q/k ([bh][n][64]) and v^T ([bh][d][n])
// ---------------------------------------------------------------------------
__global__ __launch_bounds__(256) void k_qkv(
        const unsigned short* __restrict__ Abf, const unsigned short* __restrict__ Wt,
        const float* __restrict__ bq, const float* __restrict__ bk, const float* __restrict__ bv,
        unsigned short* __restrict__ q_bf, unsigned short* __restrict__ k_bf,
        unsigned short* __restrict__ v_bf_t) {
    __shared__ unsigned short Al[2][128 * 32];
    __shared__ unsigned short Bl[2][128 * 32];
    __shared__ unsigned short vstage[128][136];

    const int tid = threadIdx.x;
    const int w = tid >> 6, lane = tid & 63;
    const int il = lane & 31, hi = lane >> 5;
    const int wr = w >> 1, wc = w & 1;
    const int rowBase = blockIdx.x * 128;
    const int colBase = blockIdx.y * 128;
    const int sel = colBase / HH;
    const int jjBase0 = colBase - sel * HH;
    const float* bias = (sel == 0) ? bq : (sel == 1) ? bk : bv;

    f32x16 acc[2][2] = {};

    auto STAGE = [&](int buf, int k0) {
#pragma unroll
        for (int c = 0; c < 2; ++c) {
            int e = tid + c * 256;
            int row = e >> 2;
            int cb = (e & 3) << 4;
            int sc = cb ^ (((row >> 1) & 3) << 4);
            __builtin_amdgcn_global_load_lds(
                (const __attribute__((address_space(1))) unsigned int*)(Abf + (size_t)(rowBase + row) * HH + k0 + (sc >> 1)),
                (__attribute__((address_space(3))) unsigned int*)(&Al[buf][row * 32 + (cb >> 1)]), 16, 0, 0);
            __builtin_amdgcn_global_load_lds(
                (const __attribute__((address_space(1))) unsigned int*)(Wt + (size_t)(colBase + row) * HH + k0 + (sc >> 1)),
                (__attribute__((address_space(3))) unsigned int*)(&Bl[buf][row * 32 + (cb >> 1)]), 16, 0, 0);
        }
    };

    STAGE(0, 0);
    __syncthreads();
    for (int t = 0; t < 24; ++t) {
        int buf = t & 1;
        if (t < 23) STAGE(buf ^ 1, (t + 1) * 32);
#pragma unroll
        for (int ks = 0; ks < 2; ++ks) {
            bf16x8 af[2], bfr[2];
            int cb = (ks << 5) + (hi << 4);
#pragma unroll
            for (int t2 = 0; t2 < 2; ++t2) {
                int rrow = wr * 64 + t2 * 32 + il;
                af[t2] = *reinterpret_cast<const bf16x8*>(
                    &Al[buf][rrow * 32 + ((cb ^ (((rrow >> 1) & 3) << 4)) >> 1)]);
                int crow = wc * 64 + t2 * 32 + il;
                bfr[t2] = *reinterpret_cast<const bf16x8*>(
                    &Bl[buf][crow * 32 + ((cb ^ (((crow >> 1) & 3) << 4)) >> 1)]);
            }
            acc[0][0] = MFMA32(af[0], bfr[0], acc[0][0], 0, 0, 0);
            acc[0][1] = MFMA32(af[0], bfr[1], acc[0][1], 0, 0, 0);
            acc[1][0] = MFMA32(af[1], bfr[0], acc[1][0], 0, 0, 0);
            acc[1][1] = MFMA32(af[1], bfr[1], acc[1][1], 0, 0, 0);
        }
        __syncthreads();
    }

    if (sel < 2) {
        unsigned short* outp = (sel == 0) ? q_bf : k_bf;
        float scale = (sel == 0) ? 0.125f : 1.0f;
#pragma unroll
        for (int rt = 0; rt < 2; ++rt)
#pragma unroll
            for (int ct = 0; ct < 2; ++ct) {
                int jjB = jjBase0 + wc * 64 + ct * 32;
                int h = jjB >> 6, d = (jjB & 63) + il;
                float bias_v = bias[jjB + il];
#pragma unroll
                for (int r = 0; r < 16; ++r) {
                    int row = rowBase + wr * 64 + rt * 32 + ((r & 3) + 8 * (r >> 2) + 4 * hi);
                    int b = row >> 8, n = row & 255;
                    outp[((size_t)(b * NHEADS + h) * NN + n) * DH + d] =
                        f2bf((acc[rt][ct][r] + bias_v) * scale);
                }
            }
    } else {
#pragma unroll
        for (int rt = 0; rt < 2; ++rt)
#pragma unroll
            for (int ct = 0; ct < 2; ++ct) {
                int jjB = jjBase0 + wc * 64 + ct * 32;
                float bias_v = bias[jjB + il];
#pragma unroll
                for (int r = 0; r < 16; ++r) {
                    int rl = wr * 64 + rt * 32 + ((r & 3) + 8 * (r >> 2) + 4 * hi);
                    vstage[wc * 64 + ct * 32 + il][rl] = f2bf(acc[rt][ct][r] + bias_v);
                }
            }
        __syncthreads();
        int b = rowBase >> 8, n0 = rowBase & 255;
        int h0 = jjBase0 >> 6;
#pragma unroll
        for (int l = 0; l < 8; ++l) {
            int e = tid + l * 256;
            int cl = e >> 4;
            int nch = e & 15;
            size_t orow = (size_t)(b * NHEADS + h0 + (cl >> 6)) * DH + (cl & 63);
            *reinterpret_cast<bf16x8*>(&v_bf_t[orow * NN + n0 + nch * 8]) =
                *reinterpret_cast<const bf16x8*>(&vstage[cl][nch * 8]);
        }
    }
}

// ---------------------------------------------------------------------------
// Kernel 3: two-pass MFMA attention, 1 wave per block (64 thr), 32 q-rows.
// Pass 1: QK^T + struct_w + bias -> online (m, sum). Pass 2: recompute tile,
// P = exp(S-m)/sum, histogram + w-write (nontemporal) + PV from regs.
// grid = 3072 (bh x 8 i-tiles, XCD-chunked). No barriers (single wave).
// ---------------------------------------------------------------------------
__global__ __launch_bounds__(64, 3) void k_attn(
        const unsigned short* __restrict__ q_bf, const unsigned short* __restrict__ k_bf,
        const unsigned short* __restrict__ v_bf_t,
        const unsigned short* __restrict__ skv_bf, const unsigned short* __restrict__ svv_t_bf,
        const float* __restrict__ bias,
        float* __restrict__ wout, unsigned short* __restrict__ attn_out) {
    __shared__ __align__(16) float qs_s[32][36];   // qs[i][vocab]
    __shared__ __align__(16) float wsum[32][40];   // histogram (cols 35..39 zero)
    __shared__ __align__(16) float bias_s[NN];
    __shared__ unsigned P2[16][33];                // packed P pairs [pair][i-row]

    const int bx0 = blockIdx.x;
    const int bx = (bx0 & 7) * 384 + (bx0 >> 3);   // XCD-chunked
    const int bh = bx >> 3, itile = bx & 7;
    const int b = bh / NHEADS, h = bh - b * NHEADS;
    const int lane = threadIdx.x;
    const int il = lane & 31, hi = lane >> 5;
    const int i0 = itile * 32;
    const int ig = i0 + il;

    *reinterpret_cast<float4*>(&bias_s[lane * 4]) =
        *reinterpret_cast<const float4*>(&bias[b * NN + lane * 4]);

    // Q fragments
    bf16x8 qf[4];
#pragma unroll
    for (int kt = 0; kt < 4; ++kt)
        qf[kt] = *reinterpret_cast<const bf16x8*>(
            &q_bf[((size_t)(bh * NN + ig)) * 64 + kt * 16 + 8 * hi]);

    // qs = Q @ skv^T
    {
        f32x16 qa0 = {}, qa1 = {};
#pragma unroll
        for (int kt = 0; kt < 4; ++kt) {
            bf16x8 s0 = *reinterpret_cast<const bf16x8*>(&skv_bf[(size_t)il * 64 + kt * 16 + 8 * hi]);
            bf16x8 s1 = *reinterpret_cast<const bf16x8*>(&skv_bf[(size_t)(32 + il) * 64 + kt * 16 + 8 * hi]);
            qa0 = MFMA32(qf[kt], s0, qa0, 0, 0, 0);
            qa1 = MFMA32(qf[kt], s1, qa1, 0, 0, 0);
        }
#pragma unroll
        for (int r = 0; r < 16; ++r) {
            int ir = (r & 3) + 8 * (r >> 2) + 4 * hi;
            qs_s[ir][il] = qa0[r];
            if (il < 3) qs_s[ir][32 + il] = qa1[r];
        }
    }
    float qlo = qs_s[il][0], qhiv = qs_s[il][34];

    // S-tile compute (recomputable): S^T tile jt (j=jt*32.., i=il), + struct_w + bias
    auto computeS = [&](int jt) -> f32x16 {
        f32x16 s = {};
#pragma unroll
        for (int kt = 0; kt < 4; ++kt) {
            bf16x8 kf = *reinterpret_cast<const bf16x8*>(
                &k_bf[((size_t)(bh * NN + jt * 32 + il)) * 64 + kt * 16 + 8 * hi]);
            s = MFMA32(kf, qf[kt], s, 0, 0, 0);
        }
#pragma unroll
        for (int rg = 0; rg < 4; ++rg) {
            int j0 = jt * 32 + rg * 8 + 4 * hi;
            float4 bv4 = *reinterpret_cast<const float4*>(&bias_s[j0]);
            float bvf[4] = {bv4.x, bv4.y, bv4.z, bv4.w};
#pragma unroll
            for (int e = 0; e < 4; ++e) {
                int dd = j0 + e - ig;
                float sw = (dd < -16) ? qlo : (dd > 16) ? qhiv : qs_s[il][dd + 17];
                s[rg * 4 + e] += bvf[e] + sw;
            }
        }
        return s;
    };

    // pass 1: online max/sum
    float m = -3.4e38f, sum = 0.f;
#pragma unroll
    for (int jt = 0; jt < 8; ++jt) {
        f32x16 s = computeS(jt);
        float tm = s[0];
#pragma unroll
        for (int r = 1; r < 16; ++r) tm = fmaxf(tm, s[r]);
        float nm = fmaxf(m, tm);
        float acc = 0.f;
#pragma unroll
        for (int r = 0; r < 16; ++r) acc += __expf(s[r] - nm);
        sum = sum * __expf(m - nm) + acc;
        m = nm;
    }
    {
        float M = fmaxf(m, __shfl_xor(m, 32));
        float sadj = sum * __expf(m - M);
        sum = sadj + __shfl_xor(sadj, 32);
        m = M;
    }
    float inv = 1.0f / sum;

    // zero histogram
#pragma unroll
    for (int z = 0; z < 5; ++z)
        *reinterpret_cast<float4*>(&((float*)wsum)[lane * 20 + z * 4]) = float4{0.f, 0.f, 0.f, 0.f};

    // pass 2: recompute, normalize, histogram, PV, w-write
    const unsigned short* vrow0 = &v_bf_t[((size_t)bh * 64 + il) * NN];
    const unsigned short* vrow1 = &v_bf_t[((size_t)bh * 64 + 32 + il) * NN];
    f32x16 O0 = {}, O1 = {};
    float elo = 0.f, ehi = 0.f;
#pragma unroll
    for (int jt = 0; jt < 8; ++jt) {
        f32x16 s = computeS(jt);
#pragma unroll
        for (int r = 0; r < 16; ++r) s[r] = __expf(s[r] - m) * inv;
        // histogram (interior slots unique per (i, dd); edges to regs)
#pragma unroll
        for (int r = 0; r < 16; ++r) {
            int j = jt * 32 + (r & 3) + 8 * (r >> 2) + 4 * hi;
            int dd = j - ig;
            float p = s[r];
            if (dd < -16) elo += p;
            else if (dd > 16) ehi += p;
            else wsum[il][dd + 17] = p;
        }
        // pack + stage + PV
#pragma unroll
        for (int ks = 0; ks < 2; ++ks) {
            unsigned w0 = pk2(s[8 * ks + 0], s[8 * ks + 1]);
            unsigned w1 = pk2(s[8 * ks + 2], s[8 * ks + 3]);
            unsigned w2 = pk2(s[8 * ks + 4], s[8 * ks + 5]);
            unsigned w3 = pk2(s[8 * ks + 6], s[8 * ks + 7]);
            int pb = 8 * ks + 2 * hi;
            P2[pb + 0][il] = w0;
            P2[pb + 1][il] = w1;
            P2[pb + 4][il] = w2;
            P2[pb + 5][il] = w3;
            unsigned s0 = hi ? w0 : w2, s1 = hi ? w1 : w3;
            unsigned y0 = (unsigned)__shfl_xor((int)s0, 32);
            unsigned y1 = (unsigned)__shfl_xor((int)s1, 32);
            union { bf16x8 v; unsigned u[4]; } Bf;
            Bf.u[0] = hi ? y0 : w0;
            Bf.u[1] = hi ? y1 : w1;
            Bf.u[2] = hi ? w2 : y0;
            Bf.u[3] = hi ? w3 : y1;
            bf16x8 va0 = *reinterpret_cast<const bf16x8*>(&vrow0[jt * 32 + ks * 16 + 8 * hi]);
            bf16x8 va1 = *reinterpret_cast<const bf16x8*>(&vrow1[jt * 32 + ks * 16 + 8 * hi]);
            O0 = MFMA32(va0, Bf.v, O0, 0, 0, 0);
            O1 = MFMA32(va1, Bf.v, O1, 0, 0, 0);
        }
        // w-write for this jt: 4 rows x 128B per instruction, nontemporal
#pragma unroll
        for (int rr = 0; rr < 8; ++rr) {
            int sr = lane >> 4, pp = lane & 15;
            int row = rr * 4 + sr;
            unsigned u = P2[pp][row];
            f32x2 val;
            val[0] = __uint_as_float((u & 0xffffu) << 16);
            val[1] = __uint_as_float(u & 0xffff0000u);
            __builtin_nontemporal_store(val, reinterpret_cast<f32x2*>(
                &wout[((size_t)(bh * NN + i0 + row)) * NN + jt * 32 + 2 * pp]));
        }
    }

    // edge buckets
    elo += __shfl_xor(elo, 32);
    ehi += __shfl_xor(ehi, 32);
    wsum[il][0] = elo;
    wsum[il][34] = ehi;

    // struct-PV: O^T += svv^T @ wsum^T
#pragma unroll
    for (int kt = 0; kt < 3; ++kt) {
        float af[8] = {0.f, 0.f, 0.f, 0.f, 0.f, 0.f, 0.f, 0.f};
        if (!(kt == 2 && hi)) {
            float4 a0 = *reinterpret_cast<const float4*>(&wsum[il][kt * 16 + 8 * hi]);
            float4 a1 = *reinterpret_cast<const float4*>(&wsum[il][kt * 16 + 8 * hi + 4]);
            af[0] = a0.x; af[1] = a0.y; af[2] = a0.z; af[3] = a0.w;
            af[4] = a1.x; af[5] = a1.y; af[6] = a1.z; af[7] = a1.w;
        }
        bf16x8 Bf = pack8(af);
        bf16x8 sa0 = *reinterpret_cast<const bf16x8*>(&svv_t_bf[(size_t)il * 48 + kt * 16 + 8 * hi]);
        bf16x8 sa1 = *reinterpret_cast<const bf16x8*>(&svv_t_bf[(size_t)(32 + il) * 48 + kt * 16 + 8 * hi]);
        O0 = MFMA32(sa0, Bf, O0, 0, 0, 0);
        O1 = MFMA32(sa1, Bf, O1, 0, 0, 0);
    }

    // attn_out (bf16, nontemporal): lane owns row i0+il, regs span d
#pragma unroll
    for (int qq = 0; qq < 4; ++qq) {
        int d0 = 8 * qq + 4 * hi;
        u32x2 o0, o1;
        o0[0] = pk2(O0[4 * qq + 0], O0[4 * qq + 1]);
        o0[1] = pk2(O0[4 * qq + 2], O0[4 * qq + 3]);
        o1[0] = pk2(O1[4 * qq + 0], O1[4 * qq + 1]);
        o1[1] = pk2(O1[4 * qq + 2], O1[4 * qq + 3]);
        size_t base = ((size_t)(b * NN + i0 + il)) * HH + h * 64;
        __builtin_nontemporal_store(o0, reinterpret_cast<u32x2*>(&attn_out[base + d0]));
        __builtin_nontemporal_store(o1, reinterpret_cast<u32x2*>(&attn_out[base + 32 + d0]));
    }
}

// ---------------------------------------------------------------------------
// Kernel 4: O-projection MFMA GEMM + bias + relu -> bf16
// ---------------------------------------------------------------------------
__global__ __launch_bounds__(256) void k_ogemm(
        const unsigned short* __restrict__ Abf, const unsigned short* __restrict__ Bt,
        const float* __restrict__ bo, unsigned short* __restrict__ Cout) {
    __shared__ unsigned short Al[2][128 * 32];
    __shared__ unsigned short Bl[2][128 * 32];

    const int tid = threadIdx.x;
    const int w = tid >> 6, lane = tid & 63;
    const int il = lane & 31, hi = lane >> 5;
    const int wr = w >> 1, wc = w & 1;
    const int rowBase = blockIdx.x * 128;
    const int colBase = blockIdx.y * 128;

    f32x16 acc[2][2] = {};

    auto STAGE = [&](int buf, int k0) {
#pragma unroll
        for (int c = 0; c < 2; ++c) {
            int e = tid + c * 256;
            int row = e >> 2;
            int cb = (e & 3) << 4;
            int sc = cb ^ (((row >> 1) & 3) << 4);
            __builtin_amdgcn_global_load_lds(
                (const __attribute__((address_space(1))) unsigned int*)(Abf + (size_t)(rowBase + row) * HH + k0 + (sc >> 1)),
                (__attribute__((address_space(3))) unsigned int*)(&Al[buf][row * 32 + (cb >> 1)]), 16, 0, 0);
            __builtin_amdgcn_global_load_lds(
                (const __attribute__((address_space(1))) unsigned int*)(Bt + (size_t)(colBase + row) * HH + k0 + (sc >> 1)),
                (__attribute__((address_space(3))) unsigned int*)(&Bl[buf][row * 32 + (cb >> 1)]), 16, 0, 0);
        }
    };

    STAGE(0, 0);
    __syncthreads();
    for (int t = 0; t < 24; ++t) {
        int buf = t & 1;
        if (t < 23) STAGE(buf ^ 1, (t + 1) * 32);
#pragma unroll
        for (int ks = 0; ks < 2; ++ks) {
            bf16x8 af[2], bfr[2];
            int cb = (ks << 5) + (hi << 4);
#pragma unroll
            for (int t2 = 0; t2 < 2; ++t2) {
                int rrow = wr * 64 + t2 * 32 + il;
                af[t2] = *reinterpret_cast<const bf16x8*>(
                    &Al[buf][rrow * 32 + ((cb ^ (((rrow >> 1) & 3) << 4)) >> 1)]);
                int crow = wc * 64 + t2 * 32 + il;
                bfr[t2] = *reinterpret_cast<const bf16x8*>(
                    &Bl[buf][crow * 32 + ((cb ^ (((crow >> 1) & 3) << 4)) >> 1)]);
            }
            acc[0][0] = MFMA32(af[0], bfr[0], acc[0][0], 0, 0, 0);
            acc[0][1] = MFMA32(af[0], bfr[1], acc[0][1], 0, 0, 0);
            acc[1][0] = MFMA32(af[1], bfr[0], acc[1][0], 0, 0, 0);
            acc[1][1] = MFMA32(af[1], bfr[1], acc[1][1], 0, 0, 0);
        }
        __syncthreads();
    }

#pragma unroll
    for (int rt = 0; rt < 2; ++rt)
#pragma unroll
        for (int ct = 0; ct < 2; ++ct) {
            int col = colBase + wc * 64 + ct * 32 + il;
            float bias_v = bo[col];
#pragma unroll
            for (int r = 0; r < 16; ++r) {
                int row = rowBase + wr * 64 + rt * 32 + ((r & 3) + 8 * (r >> 2) + 4 * hi);
                Cout[(size_t)row * HH + col] = f2bf(fmaxf(acc[rt][ct][r] + bias_v, 0.f));
            }
        }
}

// ---------------------------------------------------------------------------
// Kernel 5: final LayerNorm(nodes + proj_bf16), single-pass + shfl
// ---------------------------------------------------------------------------
__global__ __launch_bounds__(256) void k_ln(
        const float* __restrict__ nodes, const unsigned short* __restrict__ proj,
        const float* __restrict__ g, const float* __restrict__ bta,
        float* __restrict__ out) {
    __shared__ float red[2][4];
    int row = blockIdx.x;
    int tid = threadIdx.x;
    int w = tid >> 6, lane = tid & 63;
    float x[3];
    float s = 0.f, s2 = 0.f;
#pragma unroll
    for (int l = 0; l < 3; ++l) {
        int c = tid + l * 256;
        float pv = __uint_as_float(((unsigned)proj[(size_t)row * HH + c]) << 16);
        x[l] = nodes[(size_t)row * HH + c] + pv;
        s += x[l];
        s2 += x[l] * x[l];
    }
#pragma unroll
    for (int off = 32; off > 0; off >>= 1) {
        s += __shfl_xor(s, off);
        s2 += __shfl_xor(s2, off);
    }
    if (lane == 0) { red[0][w] = s; red[1][w] = s2; }
    __syncthreads();
    float ts = red[0][0] + red[0][1] + red[0][2] + red[0][3];
    float ts2 = red[1][0] + red[1][1] + red[1][2] + red[1][3];
    float mean = ts / HH;
    float var = ts2 / HH - mean * mean;
    float inv = rsqrtf(fmaxf(var, 0.f) + 1e-5f);
#pragma unroll
    for (int l = 0; l < 3; ++l) {
        int c = tid + l * 256;
        out[(size_t)row * HH + c] = (x[l] - mean) * inv * g[c] + bta[c];
    }
}

// ---------------------------------------------------------------------------
extern "C" void kernel_launch(void* const* d_in, const int* in_sizes, int n_in,
                              void* d_out, int out_size, void* d_ws, size_t ws_size,
                              hipStream_t stream) {
    const float* nodes     = (const float*)d_in[0];
    const float* bias      = (const float*)d_in[1];
    const float* pos_table = (const float*)d_in[3];
    const float* Wq = (const float*)d_in[4];  const float* bq = (const float*)d_in[5];
    const float* Wk = (const float*)d_in[6];  const float* bk = (const float*)d_in[7];
    const float* Wv = (const float*)d_in[8];  const float* bv = (const float*)d_in[9];
    const float* Wsk = (const float*)d_in[10]; const float* bsk = (const float*)d_in[11];
    const float* Wsv = (const float*)d_in[12]; const float* bsv = (const float*)d_in[13];
    const float* Wo = (const float*)d_in[14]; const float* bo = (const float*)d_in[15];
    const float* g_path = (const float*)d_in[16]; const float* b_path = (const float*)d_in[17];
    const float* g_norm = (const float*)d_in[18]; const float* b_norm = (const float*)d_in[19];

    float* out0 = (float*)d_out;                         // (B,N,H)
    float* wout = out0 + (size_t)BB * NN * HH;           // (B,HEADS,N,N)

    const size_t per = (size_t)BB * NN * HH;             // 6,291,456 elements
    char* p = (char*)d_ws;
    unsigned short* q_bf    = (unsigned short*)p; p += per * 2;
    unsigned short* k_bf    = (unsigned short*)p; p += per * 2;
    unsigned short* v_bf_t  = (unsigned short*)p; p += per * 2;
    unsigned short* skv_bf  = (unsigned short*)p; p += 64 * 64 * 2;
    unsigned short* svv_t   = (unsigned short*)p; p += 64 * 48 * 2;
    unsigned short* nodes_bf= (unsigned short*)p; p += per * 2;
    unsigned short* Wt      = (unsigned short*)p; p += (size_t)4 * HH * HH * 2;
    unsigned short* attn_bf = (unsigned short*)p; p += per * 2;
    unsigned short* proj_bf = v_bf_t;   // v^T dead after k_attn

    k_cast<<<per / 4 / 256, 256, 0, stream>>>(nodes, nodes_bf);

    dim3 gw(12, 12, 4);
    k_prep_w<<<gw, 256, 0, stream>>>(Wq, Wk, Wv, Wo, Wt);

    k_vocab<<<64, 128, 0, stream>>>(pos_table, g_path, b_path, Wsk, bsk, Wsv, bsv, skv_bf, svv_t);

    dim3 g2(64, 18);
    k_qkv<<<g2, 256, 0, stream>>>(nodes_bf, Wt, bq, bk, bv, q_bf, k_bf, v_bf_t);

    k_attn<<<BB * NHEADS * 8, 64, 0, stream>>>(q_bf, k_bf, v_bf_t, skv_bf, svv_t, bias, wout, attn_bf);

    dim3 g4(64, 6);
    k_ogemm<<<g4, 256, 0, stream>>>(attn_bf, Wt + (size_t)3 * HH * HH, bo, proj_bf);

    k_ln<<<BB * NN, 256, 0, stream>>>(nodes, proj_bf, g_norm, b_norm, out0);
}

// Round 6
// 224.952 us; speedup vs baseline: 1.9961x; 1.9961x over previous
//
#include <hip/hip_runtime.h>
#include <hip/hip_bf16.h>

#define BB 32
#define NN 256
#define HH 768
#define NHEADS 12
#define DH 64
#define PHDIM 128
#define NVOCAB 35

typedef short bf16x8 __attribute__((ext_vector_type(8)));
typedef float f32x16 __attribute__((ext_vector_type(16)));
typedef unsigned u32x2 __attribute__((ext_vector_type(2)));

#define MFMA32 __builtin_amdgcn_mfma_f32_32x32x16_bf16

// round-to-nearest-even f32 -> bf16 bits
__device__ __forceinline__ unsigned short f2bf(float f) {
    unsigned u = __float_as_uint(f);
    unsigned r = (u + 0x7fffu + ((u >> 16) & 1u)) >> 16;
    return (unsigned short)r;
}

__device__ __forceinline__ unsigned pk2(float a, float b) {
    return (unsigned)f2bf(a) | ((unsigned)f2bf(b) << 16);
}

__device__ __forceinline__ bf16x8 pack8(const float f[8]) {
    bf16x8 r;
#pragma unroll
    for (int e = 0; e < 8; ++e) r[e] = (short)f2bf(f[e]);
    return r;
}

// ---------------------------------------------------------------------------
// Kernel 0a: cast nodes f32 -> bf16
// ---------------------------------------------------------------------------
__global__ __launch_bounds__(256) void k_cast(const float* __restrict__ in,
                                              unsigned short* __restrict__ out) {
    int i = (blockIdx.x * 256 + threadIdx.x) * 4;
    float4 v = *reinterpret_cast<const float4*>(&in[i]);
    ushort4 o;
    o.x = f2bf(v.x); o.y = f2bf(v.y); o.z = f2bf(v.z); o.w = f2bf(v.w);
    *reinterpret_cast<ushort4*>(&out[i]) = o;
}

// ---------------------------------------------------------------------------
// Kernel 0b: transpose+cast weights -> Wt[z][col][k] bf16 (z: Wq,Wk,Wv,Wo)
// ---------------------------------------------------------------------------
__global__ __launch_bounds__(256) void k_prep_w(
        const float* __restrict__ Wq, const float* __restrict__ Wk,
        const float* __restrict__ Wv, const float* __restrict__ Wo,
        unsigned short* __restrict__ Wt) {
    __shared__ unsigned short tile[64][72];
    int z = blockIdx.z;
    const float* W = (z == 0) ? Wq : (z == 1) ? Wk : (z == 2) ? Wv : Wo;
    unsigned short* out = Wt + (size_t)z * HH * HH;
    int k0 = blockIdx.x * 64, c0 = blockIdx.y * 64;
    int tid = threadIdx.x;
#pragma unroll
    for (int l = 0; l < 16; ++l) {
        int e = tid + l * 256;
        int r = e >> 6, c = e & 63;
        tile[c][r] = f2bf(W[(size_t)(k0 + r) * HH + c0 + c]);
    }
    __syncthreads();
#pragma unroll
    for (int l = 0; l < 2; ++l) {
        int e = tid + l * 256;
        int c = e >> 3, ch = e & 7;
        *reinterpret_cast<bf16x8*>(&out[(size_t)(c0 + c) * HH + k0 + ch * 8]) =
            *reinterpret_cast<const bf16x8*>(&tile[c][ch * 8]);
    }
}

// ---------------------------------------------------------------------------
// Kernel 1: LN(pos_table) @ Wsk/Wsv -> bf16 vocab tables
// ---------------------------------------------------------------------------
__global__ void k_vocab(const float* __restrict__ pos_table,
                        const float* __restrict__ g_path, const float* __restrict__ b_path,
                        const float* __restrict__ Wsk, const float* __restrict__ bsk,
                        const float* __restrict__ Wsv, const float* __restrict__ bsv,
                        unsigned short* __restrict__ skv_bf, unsigned short* __restrict__ svv_t_bf) {
    int v = blockIdx.x;
    int t = threadIdx.x;  // 128
    if (v >= NVOCAB) {
        if (t < 64) skv_bf[v * 64 + t] = 0;
        else if (v < 48) svv_t_bf[(t - 64) * 48 + v] = 0;
        return;
    }
    __shared__ float x[PHDIM];
    __shared__ float red[PHDIM];
    float xv = pos_table[v * PHDIM + t];
    red[t] = xv;
    __syncthreads();
    for (int s = 64; s > 0; s >>= 1) { if (t < s) red[t] += red[t + s]; __syncthreads(); }
    float mean = red[0] / PHDIM;
    __syncthreads();
    float c = xv - mean;
    red[t] = c * c;
    __syncthreads();
    for (int s = 64; s > 0; s >>= 1) { if (t < s) red[t] += red[t + s]; __syncthreads(); }
    float var = red[0] / PHDIM;
    float ln = (xv - mean) * rsqrtf(var + 1e-5f) * g_path[t] + b_path[t];
    __syncthreads();
    x[t] = ln;
    __syncthreads();
    if (t < 64) {
        float acc = bsk[t];
        for (int p = 0; p < PHDIM; ++p) acc += x[p] * Wsk[p * DH + t];
        skv_bf[v * 64 + t] = f2bf(acc);
    } else {
        int d = t - 64;
        float acc = bsv[d];
        for (int p = 0; p < PHDIM; ++p) acc += x[p] * Wsv[p * DH + d];
        svv_t_bf[d * 48 + v] = f2bf(acc);
    }
}

// ---------------------------------------------------------------------------
// Kernel 2: QKV MFMA GEMM -> bf16 q/k ([bh][n][64]) and v^T ([bh][d][n])
// ---------------------------------------------------------------------------
__global__ __launch_bounds__(256) void k_qkv(
        const unsigned short* __restrict__ Abf, const unsigned short* __restrict__ Wt,
        const float* __restrict__ bq, const float* __restrict__ bk, const float* __restrict__ bv,
        unsigned short* __restrict__ q_bf, unsigned short* __restrict__ k_bf,
        unsigned short* __restrict__ v_bf_t) {
    __shared__ unsigned short Al[2][128 * 32];
    __shared__ unsigned short Bl[2][128 * 32];
    __shared__ unsigned short vstage[128][136];

    const int tid = threadIdx.x;
    const int w = tid >> 6, lane = tid & 63;
    const int il = lane & 31, hi = lane >> 5;
    const int wr = w >> 1, wc = w & 1;
    const int rowBase = blockIdx.x * 128;
    const int colBase = blockIdx.y * 128;
    const int sel = colBase / HH;
    const int jjBase0 = colBase - sel * HH;
    const float* bias = (sel == 0) ? bq : (sel == 1) ? bk : bv;

    f32x16 acc[2][2] = {};

    auto STAGE = [&](int buf, int k0) {
#pragma unroll
        for (int c = 0; c < 2; ++c) {
            int e = tid + c * 256;
            int row = e >> 2;
            int cb = (e & 3) << 4;
            int sc = cb ^ (((row >> 1) & 3) << 4);
            __builtin_amdgcn_global_load_lds(
                (const __attribute__((address_space(1))) unsigned int*)(Abf + (size_t)(rowBase + row) * HH + k0 + (sc >> 1)),
                (__attribute__((address_space(3))) unsigned int*)(&Al[buf][row * 32 + (cb >> 1)]), 16, 0, 0);
            __builtin_amdgcn_global_load_lds(
                (const __attribute__((address_space(1))) unsigned int*)(Wt + (size_t)(colBase + row) * HH + k0 + (sc >> 1)),
                (__attribute__((address_space(3))) unsigned int*)(&Bl[buf][row * 32 + (cb >> 1)]), 16, 0, 0);
        }
    };

    STAGE(0, 0);
    __syncthreads();
    for (int t = 0; t < 24; ++t) {
        int buf = t & 1;
        if (t < 23) STAGE(buf ^ 1, (t + 1) * 32);
#pragma unroll
        for (int ks = 0; ks < 2; ++ks) {
            bf16x8 af[2], bfr[2];
            int cb = (ks << 5) + (hi << 4);
#pragma unroll
            for (int t2 = 0; t2 < 2; ++t2) {
                int rrow = wr * 64 + t2 * 32 + il;
                af[t2] = *reinterpret_cast<const bf16x8*>(
                    &Al[buf][rrow * 32 + ((cb ^ (((rrow >> 1) & 3) << 4)) >> 1)]);
                int crow = wc * 64 + t2 * 32 + il;
                bfr[t2] = *reinterpret_cast<const bf16x8*>(
                    &Bl[buf][crow * 32 + ((cb ^ (((crow >> 1) & 3) << 4)) >> 1)]);
            }
            acc[0][0] = MFMA32(af[0], bfr[0], acc[0][0], 0, 0, 0);
            acc[0][1] = MFMA32(af[0], bfr[1], acc[0][1], 0, 0, 0);
            acc[1][0] = MFMA32(af[1], bfr[0], acc[1][0], 0, 0, 0);
            acc[1][1] = MFMA32(af[1], bfr[1], acc[1][1], 0, 0, 0);
        }
        __syncthreads();
    }

    if (sel < 2) {
        unsigned short* outp = (sel == 0) ? q_bf : k_bf;
        float scale = (sel == 0) ? 0.125f : 1.0f;
#pragma unroll
        for (int rt = 0; rt < 2; ++rt)
#pragma unroll
            for (int ct = 0; ct < 2; ++ct) {
                int jjB = jjBase0 + wc * 64 + ct * 32;
                int h = jjB >> 6, d = (jjB & 63) + il;
                float bias_v = bias[jjB + il];
#pragma unroll
                for (int r = 0; r < 16; ++r) {
                    int row = rowBase + wr * 64 + rt * 32 + ((r & 3) + 8 * (r >> 2) + 4 * hi);
                    int b = row >> 8, n = row & 255;
                    outp[((size_t)(b * NHEADS + h) * NN + n) * DH + d] =
                        f2bf((acc[rt][ct][r] + bias_v) * scale);
                }
            }
    } else {
#pragma unroll
        for (int rt = 0; rt < 2; ++rt)
#pragma unroll
            for (int ct = 0; ct < 2; ++ct) {
                int jjB = jjBase0 + wc * 64 + ct * 32;
                float bias_v = bias[jjB + il];
#pragma unroll
                for (int r = 0; r < 16; ++r) {
                    int rl = wr * 64 + rt * 32 + ((r & 3) + 8 * (r >> 2) + 4 * hi);
                    vstage[wc * 64 + ct * 32 + il][rl] = f2bf(acc[rt][ct][r] + bias_v);
                }
            }
        __syncthreads();
        int b = rowBase >> 8, n0 = rowBase & 255;
        int h0 = jjBase0 >> 6;
#pragma unroll
        for (int l = 0; l < 8; ++l) {
            int e = tid + l * 256;
            int cl = e >> 4;
            int nch = e & 15;
            size_t orow = (size_t)(b * NHEADS + h0 + (cl >> 6)) * DH + (cl & 63);
            *reinterpret_cast<bf16x8*>(&v_bf_t[orow * NN + n0 + nch * 8]) =
                *reinterpret_cast<const bf16x8*>(&vstage[cl][nch * 8]);
        }
    }
}

// ---------------------------------------------------------------------------
// Kernel 3: MFMA attention (round-3 structure: 4 waves, one pass, reg PV)
// with full-1KB-row wout writes via per-wave LDS staging.
// grid = 768 (bh x 2 halves, XCD-chunked), 256 threads.
// ---------------------------------------------------------------------------
__global__ __launch_bounds__(256, 2) void k_attn(
        const unsigned short* __restrict__ q_bf, const unsigned short* __restrict__ k_bf,
        const unsigned short* __restrict__ v_bf_t,
        const unsigned short* __restrict__ skv_bf, const unsigned short* __restrict__ svv_t_bf,
        const float* __restrict__ bias,
        float* __restrict__ wout, unsigned short* __restrict__ attn_out) {
    __shared__ float qs_ws[4][32][48];      // per-wave: qs then wsum
    __shared__ unsigned P2h[4][16][130];    // per-wave: packed P pairs, 16-row half
    __shared__ float bias_s[NN];

    const int bx0 = blockIdx.x;
    const int bx = (bx0 & 7) * 96 + (bx0 >> 3);   // XCD-chunked
    const int bh = bx >> 1, half = bx & 1;
    const int b = bh / NHEADS, h = bh - b * NHEADS;
    const int tid = threadIdx.x;
    const int w = tid >> 6, lane = tid & 63;
    const int il = lane & 31, hi = lane >> 5;
    const int i0 = half * 128 + w * 32;
    const int ig = i0 + il;

    bias_s[tid] = bias[b * NN + tid];

    // Q fragments
    bf16x8 qf[4];
#pragma unroll
    for (int kt = 0; kt < 4; ++kt)
        qf[kt] = *reinterpret_cast<const bf16x8*>(
            &q_bf[((size_t)(bh * NN + ig)) * 64 + kt * 16 + 8 * hi]);

    // qs = Q @ skv^T (per-wave LDS, no barrier)
    {
        f32x16 qa0 = {}, qa1 = {};
#pragma unroll
        for (int kt = 0; kt < 4; ++kt) {
            bf16x8 s0 = *reinterpret_cast<const bf16x8*>(&skv_bf[(size_t)il * 64 + kt * 16 + 8 * hi]);
            bf16x8 s1 = *reinterpret_cast<const bf16x8*>(&skv_bf[(size_t)(32 + il) * 64 + kt * 16 + 8 * hi]);
            qa0 = MFMA32(qf[kt], s0, qa0, 0, 0, 0);
            qa1 = MFMA32(qf[kt], s1, qa1, 0, 0, 0);
        }
#pragma unroll
        for (int r = 0; r < 16; ++r) {
            int ir = (r & 3) + 8 * (r >> 2) + 4 * hi;
            qs_ws[w][ir][il] = qa0[r];
            if (il < 3) qs_ws[w][ir][32 + il] = qa1[r];
        }
    }

    // QK^T: S^T tiles (j x i)
    f32x16 S[8] = {};
#pragma unroll
    for (int jt = 0; jt < 8; ++jt) {
#pragma unroll
        for (int kt = 0; kt < 4; ++kt) {
            bf16x8 kf = *reinterpret_cast<const bf16x8*>(
                &k_bf[((size_t)(bh * NN + jt * 32 + il)) * 64 + kt * 16 + 8 * hi]);
            S[jt] = MFMA32(kf, qf[kt], S[jt], 0, 0, 0);
        }
    }

    __syncthreads();   // bias_s ready (only cross-wave dependency)

    // add struct_w (clamped qs lookup) + bias
    {
        float qlo = qs_ws[w][il][0], qhi = qs_ws[w][il][34];
#pragma unroll
        for (int jt = 0; jt < 8; ++jt) {
#pragma unroll
            for (int rg = 0; rg < 4; ++rg) {
                int j0 = jt * 32 + rg * 8 + 4 * hi;
                float4 bv4 = *reinterpret_cast<const float4*>(&bias_s[j0]);
                float bvf[4] = {bv4.x, bv4.y, bv4.z, bv4.w};
#pragma unroll
                for (int e = 0; e < 4; ++e) {
                    int dd = j0 + e - ig;
                    float sw = (dd < -16) ? qlo : (dd > 16) ? qhi : qs_ws[w][il][dd + 17];
                    S[jt][rg * 4 + e] += bvf[e] + sw;
                }
            }
        }
    }

    // register softmax (row split between lane and lane^32)
    float m = -3.4e38f;
#pragma unroll
    for (int jt = 0; jt < 8; ++jt)
#pragma unroll
        for (int r = 0; r < 16; ++r) m = fmaxf(m, S[jt][r]);
    m = fmaxf(m, __shfl_xor(m, 32));
    float sum = 0.f;
#pragma unroll
    for (int jt = 0; jt < 8; ++jt)
#pragma unroll
        for (int r = 0; r < 16; ++r) { float p = __expf(S[jt][r] - m); S[jt][r] = p; sum += p; }
    sum += __shfl_xor(sum, 32);
    float inv = 1.0f / sum;
#pragma unroll
    for (int jt = 0; jt < 8; ++jt)
#pragma unroll
        for (int r = 0; r < 16; ++r) S[jt][r] *= inv;

    // wsum histogram into qs_ws (qs dead; per-wave, in-order DS)
#pragma unroll
    for (int c = 0; c < 24; ++c) qs_ws[w][il][hi * 24 + c] = 0.f;
    {
        float elo = 0.f, ehi = 0.f;
#pragma unroll
        for (int jt = 0; jt < 8; ++jt)
#pragma unroll
            for (int r = 0; r < 16; ++r) {
                int j = jt * 32 + (r & 3) + 8 * (r >> 2) + 4 * hi;
                int dd = j - ig;
                float p = S[jt][r];
                if (dd < -16) elo += p;
                else if (dd > 16) ehi += p;
                else qs_ws[w][il][dd + 17] = p;
            }
        atomicAdd(&qs_ws[w][il][0], elo);
        atomicAdd(&qs_ws[w][il][34], ehi);
    }

    // struct-PV (O^T): A = svv^T rows d, B = wsum^T from qs_ws
    f32x16 O0 = {}, O1 = {};
#pragma unroll
    for (int kt = 0; kt < 3; ++kt) {
        float4 a0 = *reinterpret_cast<const float4*>(&qs_ws[w][il][kt * 16 + 8 * hi]);
        float4 a1 = *reinterpret_cast<const float4*>(&qs_ws[w][il][kt * 16 + 8 * hi + 4]);
        float af[8] = {a0.x, a0.y, a0.z, a0.w, a1.x, a1.y, a1.z, a1.w};
        bf16x8 Bf = pack8(af);
        bf16x8 sa0 = *reinterpret_cast<const bf16x8*>(&svv_t_bf[(size_t)il * 48 + kt * 16 + 8 * hi]);
        bf16x8 sa1 = *reinterpret_cast<const bf16x8*>(&svv_t_bf[(size_t)(32 + il) * 48 + kt * 16 + 8 * hi]);
        O0 = MFMA32(sa0, Bf, O0, 0, 0, 0);
        O1 = MFMA32(sa1, Bf, O1, 0, 0, 0);
    }

    // main PV (O^T) entirely from regs
    const unsigned short* vrow0 = &v_bf_t[((size_t)bh * 64 + il) * NN];
    const unsigned short* vrow1 = &v_bf_t[((size_t)bh * 64 + 32 + il) * NN];
#pragma unroll
    for (int jt = 0; jt < 8; ++jt) {
#pragma unroll
        for (int ks = 0; ks < 2; ++ks) {
            unsigned w0 = pk2(S[jt][8 * ks + 0], S[jt][8 * ks + 1]);
            unsigned w1 = pk2(S[jt][8 * ks + 2], S[jt][8 * ks + 3]);
            unsigned w2 = pk2(S[jt][8 * ks + 4], S[jt][8 * ks + 5]);
            unsigned w3 = pk2(S[jt][8 * ks + 6], S[jt][8 * ks + 7]);
            unsigned s0 = hi ? w0 : w2, s1 = hi ? w1 : w3;
            unsigned y0 = (unsigned)__shfl_xor((int)s0, 32);
            unsigned y1 = (unsigned)__shfl_xor((int)s1, 32);
            union { bf16x8 v; unsigned u[4]; } Bf;
            Bf.u[0] = hi ? y0 : w0;
            Bf.u[1] = hi ? y1 : w1;
            Bf.u[2] = hi ? w2 : y0;
            Bf.u[3] = hi ? w3 : y1;
            bf16x8 va0 = *reinterpret_cast<const bf16x8*>(&vrow0[jt * 32 + ks * 16 + 8 * hi]);
            bf16x8 va1 = *reinterpret_cast<const bf16x8*>(&vrow1[jt * 32 + ks * 16 + 8 * hi]);
            O0 = MFMA32(va0, Bf.v, O0, 0, 0, 0);
            O1 = MFMA32(va1, Bf.v, O1, 0, 0, 0);
        }
    }

    // w-write: stage 16-row halves of packed P, then full-1KB-row bursts.
    // Per-wave LDS; same-wave DS ordering guarantees RAW/WAR safety.
#pragma unroll
    for (int rh = 0; rh < 2; ++rh) {
        if ((il >> 4) == rh) {
            int rr = il & 15;
#pragma unroll
            for (int jt = 0; jt < 8; ++jt)
#pragma unroll
                for (int a = 0; a < 4; ++a) {
                    u32x2 pr;
                    pr[0] = pk2(S[jt][4 * a + 0], S[jt][4 * a + 1]);
                    pr[1] = pk2(S[jt][4 * a + 2], S[jt][4 * a + 3]);
                    *reinterpret_cast<u32x2*>(&P2h[w][rr][jt * 16 + a * 4 + 2 * hi]) = pr;
                }
        }
#pragma unroll
        for (int rr = 0; rr < 16; ++rr) {
            u32x2 u = *reinterpret_cast<const u32x2*>(&P2h[w][rr][lane * 2]);
            float4 val;
            val.x = __uint_as_float((u[0] & 0xffffu) << 16);
            val.y = __uint_as_float(u[0] & 0xffff0000u);
            val.z = __uint_as_float((u[1] & 0xffffu) << 16);
            val.w = __uint_as_float(u[1] & 0xffff0000u);
            *reinterpret_cast<float4*>(
                &wout[((size_t)(bh * NN + i0 + rh * 16 + rr)) * NN + lane * 4]) = val;
        }
    }

    // attn_out (bf16): lane owns row i0+il, regs span d
#pragma unroll
    for (int qq = 0; qq < 4; ++qq) {
        int d0 = 8 * qq + 4 * hi;
        u32x2 o0, o1;
        o0[0] = pk2(O0[4 * qq + 0], O0[4 * qq + 1]);
        o0[1] = pk2(O0[4 * qq + 2], O0[4 * qq + 3]);
        o1[0] = pk2(O1[4 * qq + 0], O1[4 * qq + 1]);
        o1[1] = pk2(O1[4 * qq + 2], O1[4 * qq + 3]);
        size_t base = ((size_t)(b * NN + i0 + il)) * HH + h * 64;
        *reinterpret_cast<u32x2*>(&attn_out[base + d0]) = o0;
        *reinterpret_cast<u32x2*>(&attn_out[base + 32 + d0]) = o1;
    }
}

// ---------------------------------------------------------------------------
// Kernel 4: O-projection MFMA GEMM + bias + relu -> bf16
// ---------------------------------------------------------------------------
__global__ __launch_bounds__(256) void k_ogemm(
        const unsigned short* __restrict__ Abf, const unsigned short* __restrict__ Bt,
        const float* __restrict__ bo, unsigned short* __restrict__ Cout) {
    __shared__ unsigned short Al[2][128 * 32];
    __shared__ unsigned short Bl[2][128 * 32];

    const int tid = threadIdx.x;
    const int w = tid >> 6, lane = tid & 63;
    const int il = lane & 31, hi = lane >> 5;
    const int wr = w >> 1, wc = w & 1;
    const int rowBase = blockIdx.x * 128;
    const int colBase = blockIdx.y * 128;

    f32x16 acc[2][2] = {};

    auto STAGE = [&](int buf, int k0) {
#pragma unroll
        for (int c = 0; c < 2; ++c) {
            int e = tid + c * 256;
            int row = e >> 2;
            int cb = (e & 3) << 4;
            int sc = cb ^ (((row >> 1) & 3) << 4);
            __builtin_amdgcn_global_load_lds(
                (const __attribute__((address_space(1))) unsigned int*)(Abf + (size_t)(rowBase + row) * HH + k0 + (sc >> 1)),
                (__attribute__((address_space(3))) unsigned int*)(&Al[buf][row * 32 + (cb >> 1)]), 16, 0, 0);
            __builtin_amdgcn_global_load_lds(
                (const __attribute__((address_space(1))) unsigned int*)(Bt + (size_t)(colBase + row) * HH + k0 + (sc >> 1)),
                (__attribute__((address_space(3))) unsigned int*)(&Bl[buf][row * 32 + (cb >> 1)]), 16, 0, 0);
        }
    };

    STAGE(0, 0);
    __syncthreads();
    for (int t = 0; t < 24; ++t) {
        int buf = t & 1;
        if (t < 23) STAGE(buf ^ 1, (t + 1) * 32);
#pragma unroll
        for (int ks = 0; ks < 2; ++ks) {
            bf16x8 af[2], bfr[2];
            int cb = (ks << 5) + (hi << 4);
#pragma unroll
            for (int t2 = 0; t2 < 2; ++t2) {
                int rrow = wr * 64 + t2 * 32 + il;
                af[t2] = *reinterpret_cast<const bf16x8*>(
                    &Al[buf][rrow * 32 + ((cb ^ (((rrow >> 1) & 3) << 4)) >> 1)]);
                int crow = wc * 64 + t2 * 32 + il;
                bfr[t2] = *reinterpret_cast<const bf16x8*>(
                    &Bl[buf][crow * 32 + ((cb ^ (((crow >> 1) & 3) << 4)) >> 1)]);
            }
            acc[0][0] = MFMA32(af[0], bfr[0], acc[0][0], 0, 0, 0);
            acc[0][1] = MFMA32(af[0], bfr[1], acc[0][1], 0, 0, 0);
            acc[1][0] = MFMA32(af[1], bfr[0], acc[1][0], 0, 0, 0);
            acc[1][1] = MFMA32(af[1], bfr[1], acc[1][1], 0, 0, 0);
        }
        __syncthreads();
    }

#pragma unroll
    for (int rt = 0; rt < 2; ++rt)
#pragma unroll
        for (int ct = 0; ct < 2; ++ct) {
            int col = colBase + wc * 64 + ct * 32 + il;
            float bias_v = bo[col];
#pragma unroll
            for (int r = 0; r < 16; ++r) {
                int row = rowBase + wr * 64 + rt * 32 + ((r & 3) + 8 * (r >> 2) + 4 * hi);
                Cout[(size_t)row * HH + col] = f2bf(fmaxf(acc[rt][ct][r] + bias_v, 0.f));
            }
        }
}

// ---------------------------------------------------------------------------
// Kernel 5: final LayerNorm(nodes + proj_bf16), single-pass + shfl
// ---------------------------------------------------------------------------
__global__ __launch_bounds__(256) void k_ln(
        const float* __restrict__ nodes, const unsigned short* __restrict__ proj,
        const float* __restrict__ g, const float* __restrict__ bta,
        float* __restrict__ out) {
    __shared__ float red[2][4];
    int row = blockIdx.x;
    int tid = threadIdx.x;
    int w = tid >> 6, lane = tid & 63;
    float x[3];
    float s = 0.f, s2 = 0.f;
#pragma unroll
    for (int l = 0; l < 3; ++l) {
        int c = tid + l * 256;
        float pv = __uint_as_float(((unsigned)proj[(size_t)row * HH + c]) << 16);
        x[l] = nodes[(size_t)row * HH + c] + pv;
        s += x[l];
        s2 += x[l] * x[l];
    }
#pragma unroll
    for (int off = 32; off > 0; off >>= 1) {
        s += __shfl_xor(s, off);
        s2 += __shfl_xor(s2, off);
    }
    if (lane == 0) { red[0][w] = s; red[1][w] = s2; }
    __syncthreads();
    float ts = red[0][0] + red[0][1] + red[0][2] + red[0][3];
    float ts2 = red[1][0] + red[1][1] + red[1][2] + red[1][3];
    float mean = ts / HH;
    float var = ts2 / HH - mean * mean;
    float inv = rsqrtf(fmaxf(var, 0.f) + 1e-5f);
#pragma unroll
    for (int l = 0; l < 3; ++l) {
        int c = tid + l * 256;
        out[(size_t)row * HH + c] = (x[l] - mean) * inv * g[c] + bta[c];
    }
}

// ---------------------------------------------------------------------------
extern "C" void kernel_launch(void* const* d_in, const int* in_sizes, int n_in,
                              void* d_out, int out_size, void* d_ws, size_t ws_size,
                              hipStream_t stream) {
    const float* nodes     = (const float*)d_in[0];
    const float* bias      = (const float*)d_in[1];
    const float* pos_table = (const float*)d_in[3];
    const float* Wq = (const float*)d_in[4];  const float* bq = (const float*)d_in[5];
    const float* Wk = (const float*)d_in[6];  const float* bk = (const float*)d_in[7];
    const float* Wv = (const float*)d_in[8];  const float* bv = (const float*)d_in[9];
    const float* Wsk = (const float*)d_in[10]; const float* bsk = (const float*)d_in[11];
    const float* Wsv = (const float*)d_in[12]; const float* bsv = (const float*)d_in[13];
    const float* Wo = (const float*)d_in[14]; const float* bo = (const float*)d_in[15];
    const float* g_path = (const float*)d_in[16]; const float* b_path = (const float*)d_in[17];
    const float* g_norm = (const float*)d_in[18]; const float* b_norm = (const float*)d_in[19];

    float* out0 = (float*)d_out;                         // (B,N,H)
    float* wout = out0 + (size_t)BB * NN * HH;           // (B,HEADS,N,N)

    const size_t per = (size_t)BB * NN * HH;             // 6,291,456 elements
    char* p = (char*)d_ws;
    unsigned short* q_bf    = (unsigned short*)p; p += per * 2;
    unsigned short* k_bf    = (unsigned short*)p; p += per * 2;
    unsigned short* v_bf_t  = (unsigned short*)p; p += per * 2;
    unsigned short* skv_bf  = (unsigned short*)p; p += 64 * 64 * 2;
    unsigned short* svv_t   = (unsigned short*)p; p += 64 * 48 * 2;
    unsigned short* nodes_bf= (unsigned short*)p; p += per * 2;
    unsigned short* Wt      = (unsigned short*)p; p += (size_t)4 * HH * HH * 2;
    unsigned short* attn_bf = (unsigned short*)p; p += per * 2;
    unsigned short* proj_bf = v_bf_t;   // v^T dead after k_attn

    k_cast<<<per / 4 / 256, 256, 0, stream>>>(nodes, nodes_bf);

    dim3 gw(12, 12, 4);
    k_prep_w<<<gw, 256, 0, stream>>>(Wq, Wk, Wv, Wo, Wt);

    k_vocab<<<64, 128, 0, stream>>>(pos_table, g_path, b_path, Wsk, bsk, Wsv, bsv, skv_bf, svv_t);

    dim3 g2(64, 18);
    k_qkv<<<g2, 256, 0, stream>>>(nodes_bf, Wt, bq, bk, bv, q_bf, k_bf, v_bf_t);

    k_attn<<<BB * NHEADS * 2, 256, 0, stream>>>(q_bf, k_bf, v_bf_t, skv_bf, svv_t, bias, wout, attn_bf);

    dim3 g4(64, 6);
    k_ogemm<<<g4, 256, 0, stream>>>(attn_bf, Wt + (size_t)3 * HH * HH, bo, proj_bf);

    k_ln<<<BB * NN, 256, 0, stream>>>(nodes, proj_bf, g_norm, b_norm, out0);
}

// Round 7
// 173.833 us; speedup vs baseline: 2.5830x; 1.2941x over previous
//
#include <hip/hip_runtime.h>
#include <hip/hip_bf16.h>

#define BB 32
#define NN 256
#define HH 768
#define NHEADS 12
#define DH 64
#define PHDIM 128
#define NVOCAB 35

typedef short bf16x8 __attribute__((ext_vector_type(8)));
typedef float f32x16 __attribute__((ext_vector_type(16)));
typedef unsigned u32x2 __attribute__((ext_vector_type(2)));

#define MFMA32 __builtin_amdgcn_mfma_f32_32x32x16_bf16

// round-to-nearest-even f32 -> bf16 bits
__device__ __forceinline__ unsigned short f2bf(float f) {
    unsigned u = __float_as_uint(f);
    unsigned r = (u + 0x7fffu + ((u >> 16) & 1u)) >> 16;
    return (unsigned short)r;
}

__device__ __forceinline__ unsigned pk2(float a, float b) {
    return (unsigned)f2bf(a) | ((unsigned)f2bf(b) << 16);
}

__device__ __forceinline__ bf16x8 pack8(const float f[8]) {
    bf16x8 r;
#pragma unroll
    for (int e = 0; e < 8; ++e) r[e] = (short)f2bf(f[e]);
    return r;
}

// ---------------------------------------------------------------------------
// Kernel 0a: cast nodes f32 -> bf16
// ---------------------------------------------------------------------------
__global__ __launch_bounds__(256) void k_cast(const float* __restrict__ in,
                                              unsigned short* __restrict__ out) {
    int i = (blockIdx.x * 256 + threadIdx.x) * 4;
    float4 v = *reinterpret_cast<const float4*>(&in[i]);
    ushort4 o;
    o.x = f2bf(v.x); o.y = f2bf(v.y); o.z = f2bf(v.z); o.w = f2bf(v.w);
    *reinterpret_cast<ushort4*>(&out[i]) = o;
}

// ---------------------------------------------------------------------------
// Kernel 0b: transpose+cast weights -> Wt[z][col][k] bf16 (z: Wq,Wk,Wv,Wo)
// ---------------------------------------------------------------------------
__global__ __launch_bounds__(256) void k_prep_w(
        const float* __restrict__ Wq, const float* __restrict__ Wk,
        const float* __restrict__ Wv, const float* __restrict__ Wo,
        unsigned short* __restrict__ Wt) {
    __shared__ unsigned short tile[64][72];
    int z = blockIdx.z;
    const float* W = (z == 0) ? Wq : (z == 1) ? Wk : (z == 2) ? Wv : Wo;
    unsigned short* out = Wt + (size_t)z * HH * HH;
    int k0 = blockIdx.x * 64, c0 = blockIdx.y * 64;
    int tid = threadIdx.x;
#pragma unroll
    for (int l = 0; l < 16; ++l) {
        int e = tid + l * 256;
        int r = e >> 6, c = e & 63;
        tile[c][r] = f2bf(W[(size_t)(k0 + r) * HH + c0 + c]);
    }
    __syncthreads();
#pragma unroll
    for (int l = 0; l < 2; ++l) {
        int e = tid + l * 256;
        int c = e >> 3, ch = e & 7;
        *reinterpret_cast<bf16x8*>(&out[(size_t)(c0 + c) * HH + k0 + ch * 8]) =
            *reinterpret_cast<const bf16x8*>(&tile[c][ch * 8]);
    }
}

// ---------------------------------------------------------------------------
// Kernel 1: LN(pos_table) @ Wsk/Wsv -> bf16 vocab tables
// ---------------------------------------------------------------------------
__global__ void k_vocab(const float* __restrict__ pos_table,
                        const float* __restrict__ g_path, const float* __restrict__ b_path,
                        const float* __restrict__ Wsk, const float* __restrict__ bsk,
                        const float* __restrict__ Wsv, const float* __restrict__ bsv,
                        unsigned short* __restrict__ skv_bf, unsigned short* __restrict__ svv_t_bf) {
    int v = blockIdx.x;
    int t = threadIdx.x;  // 128
    if (v >= NVOCAB) {
        if (t < 64) skv_bf[v * 64 + t] = 0;
        else if (v < 48) svv_t_bf[(t - 64) * 48 + v] = 0;
        return;
    }
    __shared__ float x[PHDIM];
    __shared__ float red[PHDIM];
    float xv = pos_table[v * PHDIM + t];
    red[t] = xv;
    __syncthreads();
    for (int s = 64; s > 0; s >>= 1) { if (t < s) red[t] += red[t + s]; __syncthreads(); }
    float mean = red[0] / PHDIM;
    __syncthreads();
    float c = xv - mean;
    red[t] = c * c;
    __syncthreads();
    for (int s = 64; s > 0; s >>= 1) { if (t < s) red[t] += red[t + s]; __syncthreads(); }
    float var = red[0] / PHDIM;
    float ln = (xv - mean) * rsqrtf(var + 1e-5f) * g_path[t] + b_path[t];
    __syncthreads();
    x[t] = ln;
    __syncthreads();
    if (t < 64) {
        float acc = bsk[t];
        for (int p = 0; p < PHDIM; ++p) acc += x[p] * Wsk[p * DH + t];
        skv_bf[v * 64 + t] = f2bf(acc);
    } else {
        int d = t - 64;
        float acc = bsv[d];
        for (int p = 0; p < PHDIM; ++p) acc += x[p] * Wsv[p * DH + d];
        svv_t_bf[d * 48 + v] = f2bf(acc);
    }
}

// ---------------------------------------------------------------------------
// Kernel 2: QKV MFMA GEMM -> bf16 q/k ([bh][n][64]) and v^T ([bh][d][n])
// ---------------------------------------------------------------------------
__global__ __launch_bounds__(256) void k_qkv(
        const unsigned short* __restrict__ Abf, const unsigned short* __restrict__ Wt,
        const float* __restrict__ bq, const float* __restrict__ bk, const float* __restrict__ bv,
        unsigned short* __restrict__ q_bf, unsigned short* __restrict__ k_bf,
        unsigned short* __restrict__ v_bf_t) {
    __shared__ unsigned short Al[2][128 * 32];
    __shared__ unsigned short Bl[2][128 * 32];
    __shared__ unsigned short vstage[128][136];

    const int tid = threadIdx.x;
    const int w = tid >> 6, lane = tid & 63;
    const int il = lane & 31, hi = lane >> 5;
    const int wr = w >> 1, wc = w & 1;
    const int rowBase = blockIdx.x * 128;
    const int colBase = blockIdx.y * 128;
    const int sel = colBase / HH;
    const int jjBase0 = colBase - sel * HH;
    const float* bias = (sel == 0) ? bq : (sel == 1) ? bk : bv;

    f32x16 acc[2][2] = {};

    auto STAGE = [&](int buf, int k0) {
#pragma unroll
        for (int c = 0; c < 2; ++c) {
            int e = tid + c * 256;
            int row = e >> 2;
            int cb = (e & 3) << 4;
            int sc = cb ^ (((row >> 1) & 3) << 4);
            __builtin_amdgcn_global_load_lds(
                (const __attribute__((address_space(1))) unsigned int*)(Abf + (size_t)(rowBase + row) * HH + k0 + (sc >> 1)),
                (__attribute__((address_space(3))) unsigned int*)(&Al[buf][row * 32 + (cb >> 1)]), 16, 0, 0);
            __builtin_amdgcn_global_load_lds(
                (const __attribute__((address_space(1))) unsigned int*)(Wt + (size_t)(colBase + row) * HH + k0 + (sc >> 1)),
                (__attribute__((address_space(3))) unsigned int*)(&Bl[buf][row * 32 + (cb >> 1)]), 16, 0, 0);
        }
    };

    STAGE(0, 0);
    __syncthreads();
    for (int t = 0; t < 24; ++t) {
        int buf = t & 1;
        if (t < 23) STAGE(buf ^ 1, (t + 1) * 32);
#pragma unroll
        for (int ks = 0; ks < 2; ++ks) {
            bf16x8 af[2], bfr[2];
            int cb = (ks << 5) + (hi << 4);
#pragma unroll
            for (int t2 = 0; t2 < 2; ++t2) {
                int rrow = wr * 64 + t2 * 32 + il;
                af[t2] = *reinterpret_cast<const bf16x8*>(
                    &Al[buf][rrow * 32 + ((cb ^ (((rrow >> 1) & 3) << 4)) >> 1)]);
                int crow = wc * 64 + t2 * 32 + il;
                bfr[t2] = *reinterpret_cast<const bf16x8*>(
                    &Bl[buf][crow * 32 + ((cb ^ (((crow >> 1) & 3) << 4)) >> 1)]);
            }
            acc[0][0] = MFMA32(af[0], bfr[0], acc[0][0], 0, 0, 0);
            acc[0][1] = MFMA32(af[0], bfr[1], acc[0][1], 0, 0, 0);
            acc[1][0] = MFMA32(af[1], bfr[0], acc[1][0], 0, 0, 0);
            acc[1][1] = MFMA32(af[1], bfr[1], acc[1][1], 0, 0, 0);
        }
        __syncthreads();
    }

    if (sel < 2) {
        unsigned short* outp = (sel == 0) ? q_bf : k_bf;
        float scale = (sel == 0) ? 0.125f : 1.0f;
#pragma unroll
        for (int rt = 0; rt < 2; ++rt)
#pragma unroll
            for (int ct = 0; ct < 2; ++ct) {
                int jjB = jjBase0 + wc * 64 + ct * 32;
                int h = jjB >> 6, d = (jjB & 63) + il;
                float bias_v = bias[jjB + il];
#pragma unroll
                for (int r = 0; r < 16; ++r) {
                    int row = rowBase + wr * 64 + rt * 32 + ((r & 3) + 8 * (r >> 2) + 4 * hi);
                    int b = row >> 8, n = row & 255;
                    outp[((size_t)(b * NHEADS + h) * NN + n) * DH + d] =
                        f2bf((acc[rt][ct][r] + bias_v) * scale);
                }
            }
    } else {
#pragma unroll
        for (int rt = 0; rt < 2; ++rt)
#pragma unroll
            for (int ct = 0; ct < 2; ++ct) {
                int jjB = jjBase0 + wc * 64 + ct * 32;
                float bias_v = bias[jjB + il];
#pragma unroll
                for (int r = 0; r < 16; ++r) {
                    int rl = wr * 64 + rt * 32 + ((r & 3) + 8 * (r >> 2) + 4 * hi);
                    vstage[wc * 64 + ct * 32 + il][rl] = f2bf(acc[rt][ct][r] + bias_v);
                }
            }
        __syncthreads();
        int b = rowBase >> 8, n0 = rowBase & 255;
        int h0 = jjBase0 >> 6;
#pragma unroll
        for (int l = 0; l < 8; ++l) {
            int e = tid + l * 256;
            int cl = e >> 4;
            int nch = e & 15;
            size_t orow = (size_t)(b * NHEADS + h0 + (cl >> 6)) * DH + (cl & 63);
            *reinterpret_cast<bf16x8*>(&v_bf_t[orow * NN + n0 + nch * 8]) =
                *reinterpret_cast<const bf16x8*>(&vstage[cl][nch * 8]);
        }
    }
}

// ---------------------------------------------------------------------------
// Kernel 3: MFMA attention, j-split wave pairs for occupancy.
// Block = 64 q-rows (2 groups of 32) x full j; wave (g, jh) = 32 rows x 128 j.
// S[4] = 64 VGPR/wave -> 3 waves/SIMD. Softmax/O merged via small LDS.
// w written directly from S regs as f32. grid = 1536 (bh x 4 rowblocks).
// ---------------------------------------------------------------------------
__global__ __launch_bounds__(256, 3) void k_attn(
        const unsigned short* __restrict__ q_bf, const unsigned short* __restrict__ k_bf,
        const unsigned short* __restrict__ v_bf_t,
        const unsigned short* __restrict__ skv_bf, const unsigned short* __restrict__ svv_t_bf,
        const float* __restrict__ bias,
        float* __restrict__ wout, unsigned short* __restrict__ attn_out) {
    __shared__ float qs_a[2][32][48];        // per row-group: qs, then reused as wsum
    __shared__ float oex[2][32][68];         // O partial exchange per row-group
    __shared__ float pairbuf[2][2][32][2];   // (m, sum) exchange
    __shared__ float bias_s[NN];

    const int bx0 = blockIdx.x;
    const int bx = (bx0 & 7) * 192 + (bx0 >> 3);   // XCD-chunked
    const int bh = bx >> 2, rowblk = bx & 3;
    const int b = bh / NHEADS, h = bh - b * NHEADS;
    const int tid = threadIdx.x;
    const int w = tid >> 6, lane = tid & 63;
    const int g = w & 1, jh = w >> 1;
    const int il = lane & 31, hi = lane >> 5;
    const int i0 = rowblk * 64 + g * 32;
    const int ig = i0 + il;
    const int jb = jh * 128;

    bias_s[tid] = bias[b * NN + tid];

    // Q fragments (both jh waves of a pair load the same rows)
    bf16x8 qf[4];
#pragma unroll
    for (int kt = 0; kt < 4; ++kt)
        qf[kt] = *reinterpret_cast<const bf16x8*>(
            &q_bf[((size_t)(bh * NN + ig)) * 64 + kt * 16 + 8 * hi]);

    // qs = Q @ skv^T, computed once per row-group (jh==0)
    if (jh == 0) {
        f32x16 qa0 = {}, qa1 = {};
#pragma unroll
        for (int kt = 0; kt < 4; ++kt) {
            bf16x8 s0 = *reinterpret_cast<const bf16x8*>(&skv_bf[(size_t)il * 64 + kt * 16 + 8 * hi]);
            bf16x8 s1 = *reinterpret_cast<const bf16x8*>(&skv_bf[(size_t)(32 + il) * 64 + kt * 16 + 8 * hi]);
            qa0 = MFMA32(qf[kt], s0, qa0, 0, 0, 0);
            qa1 = MFMA32(qf[kt], s1, qa1, 0, 0, 0);
        }
#pragma unroll
        for (int r = 0; r < 16; ++r) {
            int ir = (r & 3) + 8 * (r >> 2) + 4 * hi;
            qs_a[g][ir][il] = qa0[r];
            if (il < 3) qs_a[g][ir][32 + il] = qa1[r];
        }
    }

    // QK^T for this wave's j-half: S[4] (reg r <-> j, lane il <-> q-row)
    f32x16 S[4] = {};
#pragma unroll
    for (int jt = 0; jt < 4; ++jt) {
#pragma unroll
        for (int kt = 0; kt < 4; ++kt) {
            bf16x8 kf = *reinterpret_cast<const bf16x8*>(
                &k_bf[((size_t)(bh * NN + jb + jt * 32 + il)) * 64 + kt * 16 + 8 * hi]);
            S[jt] = MFMA32(kf, qf[kt], S[jt], 0, 0, 0);
        }
    }

    __syncthreads();   // b1: bias_s + qs ready

    // add struct_w (clamped qs lookup) + bias
    {
        float qlo = qs_a[g][il][0], qhi = qs_a[g][il][34];
#pragma unroll
        for (int jt = 0; jt < 4; ++jt) {
#pragma unroll
            for (int rg = 0; rg < 4; ++rg) {
                int j0 = jb + jt * 32 + rg * 8 + 4 * hi;
                float4 bv4 = *reinterpret_cast<const float4*>(&bias_s[j0]);
                float bvf[4] = {bv4.x, bv4.y, bv4.z, bv4.w};
#pragma unroll
                for (int e = 0; e < 4; ++e) {
                    int dd = j0 + e - ig;
                    float sw = (dd < -16) ? qlo : (dd > 16) ? qhi : qs_a[g][il][dd + 17];
                    S[jt][rg * 4 + e] += bvf[e] + sw;
                }
            }
        }
    }

    // partial softmax over this j-half (row split lane/lane^32)
    float m = -3.4e38f;
#pragma unroll
    for (int jt = 0; jt < 4; ++jt)
#pragma unroll
        for (int r = 0; r < 16; ++r) m = fmaxf(m, S[jt][r]);
    m = fmaxf(m, __shfl_xor(m, 32));
    float sum = 0.f;
#pragma unroll
    for (int jt = 0; jt < 4; ++jt)
#pragma unroll
        for (int r = 0; r < 16; ++r) { float p = __expf(S[jt][r] - m); S[jt][r] = p; sum += p; }
    sum += __shfl_xor(sum, 32);
    if (hi == 0) { pairbuf[g][jh][il][0] = m; pairbuf[g][jh][il][1] = sum; }
    __syncthreads();   // b2: partials ready; qs no longer needed
    {
        float mo = pairbuf[g][jh ^ 1][il][0];
        float so = pairbuf[g][jh ^ 1][il][1];
        float M = fmaxf(m, mo);
        float sumT = sum * __expf(m - M) + so * __expf(mo - M);
        float scale = __expf(m - M) / sumT;
#pragma unroll
        for (int jt = 0; jt < 4; ++jt)
#pragma unroll
            for (int r = 0; r < 16; ++r) S[jt][r] *= scale;
    }

    // zero wsum (qs_a reuse): wave/hi split covers cols 0..47 per row
#pragma unroll
    for (int c = 0; c < 12; ++c) qs_a[g][il][jh * 24 + hi * 12 + c] = 0.f;

    // w-write: direct f32 from S regs (4 consecutive j per rg)
#pragma unroll
    for (int jt = 0; jt < 4; ++jt) {
#pragma unroll
        for (int rg = 0; rg < 4; ++rg) {
            float4 val;
            val.x = S[jt][rg * 4 + 0];
            val.y = S[jt][rg * 4 + 1];
            val.z = S[jt][rg * 4 + 2];
            val.w = S[jt][rg * 4 + 3];
            *reinterpret_cast<float4*>(
                &wout[((size_t)(bh * NN + ig)) * NN + jb + jt * 32 + rg * 8 + 4 * hi]) = val;
        }
    }

    __syncthreads();   // b3: wsum zeroed

    // histogram scatter (interior slots unique per (i,dd) even across jh)
    {
        float elo = 0.f, ehi = 0.f;
#pragma unroll
        for (int jt = 0; jt < 4; ++jt)
#pragma unroll
            for (int r = 0; r < 16; ++r) {
                int j = jb + jt * 32 + (r & 3) + 8 * (r >> 2) + 4 * hi;
                int dd = j - ig;
                float p = S[jt][r];
                if (dd < -16) elo += p;
                else if (dd > 16) ehi += p;
                else qs_a[g][il][dd + 17] = p;
            }
        atomicAdd(&qs_a[g][il][0], elo);
        atomicAdd(&qs_a[g][il][34], ehi);
    }

    // main PV (O^T) from regs over this wave's j-half
    const unsigned short* vrow0 = &v_bf_t[((size_t)bh * 64 + il) * NN];
    const unsigned short* vrow1 = &v_bf_t[((size_t)bh * 64 + 32 + il) * NN];
    f32x16 O0 = {}, O1 = {};
#pragma unroll
    for (int jt = 0; jt < 4; ++jt) {
#pragma unroll
        for (int ks = 0; ks < 2; ++ks) {
            unsigned w0 = pk2(S[jt][8 * ks + 0], S[jt][8 * ks + 1]);
            unsigned w1 = pk2(S[jt][8 * ks + 2], S[jt][8 * ks + 3]);
            unsigned w2 = pk2(S[jt][8 * ks + 4], S[jt][8 * ks + 5]);
            unsigned w3 = pk2(S[jt][8 * ks + 6], S[jt][8 * ks + 7]);
            unsigned s0 = hi ? w0 : w2, s1 = hi ? w1 : w3;
            unsigned y0 = (unsigned)__shfl_xor((int)s0, 32);
            unsigned y1 = (unsigned)__shfl_xor((int)s1, 32);
            union { bf16x8 v; unsigned u[4]; } Bf;
            Bf.u[0] = hi ? y0 : w0;
            Bf.u[1] = hi ? y1 : w1;
            Bf.u[2] = hi ? w2 : y0;
            Bf.u[3] = hi ? w3 : y1;
            bf16x8 va0 = *reinterpret_cast<const bf16x8*>(&vrow0[jb + jt * 32 + ks * 16 + 8 * hi]);
            bf16x8 va1 = *reinterpret_cast<const bf16x8*>(&vrow1[jb + jt * 32 + ks * 16 + 8 * hi]);
            O0 = MFMA32(va0, Bf.v, O0, 0, 0, 0);
            O1 = MFMA32(va1, Bf.v, O1, 0, 0, 0);
        }
    }

    __syncthreads();   // b4: histogram complete

    // O partial exchange: jh=1 stages, jh=0 merges + struct-PV + store
    if (jh == 1) {
#pragma unroll
        for (int qq = 0; qq < 4; ++qq) {
            int d0 = 8 * qq + 4 * hi;
            *reinterpret_cast<float4*>(&oex[g][il][d0]) =
                float4{O0[4 * qq + 0], O0[4 * qq + 1], O0[4 * qq + 2], O0[4 * qq + 3]};
            *reinterpret_cast<float4*>(&oex[g][il][32 + d0]) =
                float4{O1[4 * qq + 0], O1[4 * qq + 1], O1[4 * qq + 2], O1[4 * qq + 3]};
        }
    }
    __syncthreads();   // b5: partials staged
    if (jh == 0) {
#pragma unroll
        for (int qq = 0; qq < 4; ++qq) {
            int d0 = 8 * qq + 4 * hi;
            float4 p0 = *reinterpret_cast<const float4*>(&oex[g][il][d0]);
            float4 p1 = *reinterpret_cast<const float4*>(&oex[g][il][32 + d0]);
            O0[4 * qq + 0] += p0.x; O0[4 * qq + 1] += p0.y;
            O0[4 * qq + 2] += p0.z; O0[4 * qq + 3] += p0.w;
            O1[4 * qq + 0] += p1.x; O1[4 * qq + 1] += p1.y;
            O1[4 * qq + 2] += p1.z; O1[4 * qq + 3] += p1.w;
        }

        // struct-PV: O^T += svv^T @ wsum^T (once per row)
#pragma unroll
        for (int kt = 0; kt < 3; ++kt) {
            float4 a0 = *reinterpret_cast<const float4*>(&qs_a[g][il][kt * 16 + 8 * hi]);
            float4 a1 = *reinterpret_cast<const float4*>(&qs_a[g][il][kt * 16 + 8 * hi + 4]);
            float af[8] = {a0.x, a0.y, a0.z, a0.w, a1.x, a1.y, a1.z, a1.w};
            bf16x8 Bf = pack8(af);
            bf16x8 sa0 = *reinterpret_cast<const bf16x8*>(&svv_t_bf[(size_t)il * 48 + kt * 16 + 8 * hi]);
            bf16x8 sa1 = *reinterpret_cast<const bf16x8*>(&svv_t_bf[(size_t)(32 + il) * 48 + kt * 16 + 8 * hi]);
            O0 = MFMA32(sa0, Bf, O0, 0, 0, 0);
            O1 = MFMA32(sa1, Bf, O1, 0, 0, 0);
        }

        // attn_out (bf16): lane owns row i0+il, regs span d
#pragma unroll
        for (int qq = 0; qq < 4; ++qq) {
            int d0 = 8 * qq + 4 * hi;
            u32x2 o0, o1;
            o0[0] = pk2(O0[4 * qq + 0], O0[4 * qq + 1]);
            o0[1] = pk2(O0[4 * qq + 2], O0[4 * qq + 3]);
            o1[0] = pk2(O1[4 * qq + 0], O1[4 * qq + 1]);
            o1[1] = pk2(O1[4 * qq + 2], O1[4 * qq + 3]);
            size_t base = ((size_t)(b * NN + i0 + il)) * HH + h * 64;
            *reinterpret_cast<u32x2*>(&attn_out[base + d0]) = o0;
            *reinterpret_cast<u32x2*>(&attn_out[base + 32 + d0]) = o1;
        }
    }
}

// ---------------------------------------------------------------------------
// Kernel 4: O-projection MFMA GEMM + bias + relu -> bf16
// ---------------------------------------------------------------------------
__global__ __launch_bounds__(256) void k_ogemm(
        const unsigned short* __restrict__ Abf, const unsigned short* __restrict__ Bt,
        const float* __restrict__ bo, unsigned short* __restrict__ Cout) {
    __shared__ unsigned short Al[2][128 * 32];
    __shared__ unsigned short Bl[2][128 * 32];

    const int tid = threadIdx.x;
    const int w = tid >> 6, lane = tid & 63;
    const int il = lane & 31, hi = lane >> 5;
    const int wr = w >> 1, wc = w & 1;
    const int rowBase = blockIdx.x * 128;
    const int colBase = blockIdx.y * 128;

    f32x16 acc[2][2] = {};

    auto STAGE = [&](int buf, int k0) {
#pragma unroll
        for (int c = 0; c < 2; ++c) {
            int e = tid + c * 256;
            int row = e >> 2;
            int cb = (e & 3) << 4;
            int sc = cb ^ (((row >> 1) & 3) << 4);
            __builtin_amdgcn_global_load_lds(
                (const __attribute__((address_space(1))) unsigned int*)(Abf + (size_t)(rowBase + row) * HH + k0 + (sc >> 1)),
                (__attribute__((address_space(3))) unsigned int*)(&Al[buf][row * 32 + (cb >> 1)]), 16, 0, 0);
            __builtin_amdgcn_global_load_lds(
                (const __attribute__((address_space(1))) unsigned int*)(Bt + (size_t)(colBase + row) * HH + k0 + (sc >> 1)),
                (__attribute__((address_space(3))) unsigned int*)(&Bl[buf][row * 32 + (cb >> 1)]), 16, 0, 0);
        }
    };

    STAGE(0, 0);
    __syncthreads();
    for (int t = 0; t < 24; ++t) {
        int buf = t & 1;
        if (t < 23) STAGE(buf ^ 1, (t + 1) * 32);
#pragma unroll
        for (int ks = 0; ks < 2; ++ks) {
            bf16x8 af[2], bfr[2];
            int cb = (ks << 5) + (hi << 4);
#pragma unroll
            for (int t2 = 0; t2 < 2; ++t2) {
                int rrow = wr * 64 + t2 * 32 + il;
                af[t2] = *reinterpret_cast<const bf16x8*>(
                    &Al[buf][rrow * 32 + ((cb ^ (((rrow >> 1) & 3) << 4)) >> 1)]);
                int crow = wc * 64 + t2 * 32 + il;
                bfr[t2] = *reinterpret_cast<const bf16x8*>(
                    &Bl[buf][crow * 32 + ((cb ^ (((crow >> 1) & 3) << 4)) >> 1)]);
            }
            acc[0][0] = MFMA32(af[0], bfr[0], acc[0][0], 0, 0, 0);
            acc[0][1] = MFMA32(af[0], bfr[1], acc[0][1], 0, 0, 0);
            acc[1][0] = MFMA32(af[1], bfr[0], acc[1][0], 0, 0, 0);
            acc[1][1] = MFMA32(af[1], bfr[1], acc[1][1], 0, 0, 0);
        }
        __syncthreads();
    }

#pragma unroll
    for (int rt = 0; rt < 2; ++rt)
#pragma unroll
        for (int ct = 0; ct < 2; ++ct) {
            int col = colBase + wc * 64 + ct * 32 + il;
            float bias_v = bo[col];
#pragma unroll
            for (int r = 0; r < 16; ++r) {
                int row = rowBase + wr * 64 + rt * 32 + ((r & 3) + 8 * (r >> 2) + 4 * hi);
                Cout[(size_t)row * HH + col] = f2bf(fmaxf(acc[rt][ct][r] + bias_v, 0.f));
            }
        }
}

// ---------------------------------------------------------------------------
// Kernel 5: final LayerNorm(nodes + proj_bf16), single-pass + shfl
// ---------------------------------------------------------------------------
__global__ __launch_bounds__(256) void k_ln(
        const float* __restrict__ nodes, const unsigned short* __restrict__ proj,
        const float* __restrict__ g, const float* __restrict__ bta,
        float* __restrict__ out) {
    __shared__ float red[2][4];
    int row = blockIdx.x;
    int tid = threadIdx.x;
    int w = tid >> 6, lane = tid & 63;
    float x[3];
    float s = 0.f, s2 = 0.f;
#pragma unroll
    for (int l = 0; l < 3; ++l) {
        int c = tid + l * 256;
        float pv = __uint_as_float(((unsigned)proj[(size_t)row * HH + c]) << 16);
        x[l] = nodes[(size_t)row * HH + c] + pv;
        s += x[l];
        s2 += x[l] * x[l];
    }
#pragma unroll
    for (int off = 32; off > 0; off >>= 1) {
        s += __shfl_xor(s, off);
        s2 += __shfl_xor(s2, off);
    }
    if (lane == 0) { red[0][w] = s; red[1][w] = s2; }
    __syncthreads();
    float ts = red[0][0] + red[0][1] + red[0][2] + red[0][3];
    float ts2 = red[1][0] + red[1][1] + red[1][2] + red[1][3];
    float mean = ts / HH;
    float var = ts2 / HH - mean * mean;
    float inv = rsqrtf(fmaxf(var, 0.f) + 1e-5f);
#pragma unroll
    for (int l = 0; l < 3; ++l) {
        int c = tid + l * 256;
        out[(size_t)row * HH + c] = (x[l] - mean) * inv * g[c] + bta[c];
    }
}

// ---------------------------------------------------------------------------
extern "C" void kernel_launch(void* const* d_in, const int* in_sizes, int n_in,
                              void* d_out, int out_size, void* d_ws, size_t ws_size,
                              hipStream_t stream) {
    const float* nodes     = (const float*)d_in[0];
    const float* bias      = (const float*)d_in[1];
    const float* pos_table = (const float*)d_in[3];
    const float* Wq = (const float*)d_in[4];  const float* bq = (const float*)d_in[5];
    const float* Wk = (const float*)d_in[6];  const float* bk = (const float*)d_in[7];
    const float* Wv = (const float*)d_in[8];  const float* bv = (const float*)d_in[9];
    const float* Wsk = (const float*)d_in[10]; const float* bsk = (const float*)d_in[11];
    const float* Wsv = (const float*)d_in[12]; const float* bsv = (const float*)d_in[13];
    const float* Wo = (const float*)d_in[14]; const float* bo = (const float*)d_in[15];
    const float* g_path = (const float*)d_in[16]; const float* b_path = (const float*)d_in[17];
    const float* g_norm = (const float*)d_in[18]; const float* b_norm = (const float*)d_in[19];

    float* out0 = (float*)d_out;                         // (B,N,H)
    float* wout = out0 + (size_t)BB * NN * HH;           // (B,HEADS,N,N)

    const size_t per = (size_t)BB * NN * HH;             // 6,291,456 elements
    char* p = (char*)d_ws;
    unsigned short* q_bf    = (unsigned short*)p; p += per * 2;
    unsigned short* k_bf    = (unsigned short*)p; p += per * 2;
    unsigned short* v_bf_t  = (unsigned short*)p; p += per * 2;
    unsigned short* skv_bf  = (unsigned short*)p; p += 64 * 64 * 2;
    unsigned short* svv_t   = (unsigned short*)p; p += 64 * 48 * 2;
    unsigned short* nodes_bf= (unsigned short*)p; p += per * 2;
    unsigned short* Wt      = (unsigned short*)p; p += (size_t)4 * HH * HH * 2;
    unsigned short* attn_bf = (unsigned short*)p; p += per * 2;
    unsigned short* proj_bf = v_bf_t;   // v^T dead after k_attn

    k_cast<<<per / 4 / 256, 256, 0, stream>>>(nodes, nodes_bf);

    dim3 gw(12, 12, 4);
    k_prep_w<<<gw, 256, 0, stream>>>(Wq, Wk, Wv, Wo, Wt);

    k_vocab<<<64, 128, 0, stream>>>(pos_table, g_path, b_path, Wsk, bsk, Wsv, bsv, skv_bf, svv_t);

    dim3 g2(64, 18);
    k_qkv<<<g2, 256, 0, stream>>>(nodes_bf, Wt, bq, bk, bv, q_bf, k_bf, v_bf_t);

    k_attn<<<BB * NHEADS * 4, 256, 0, stream>>>(q_bf, k_bf, v_bf_t, skv_bf, svv_t, bias, wout, attn_bf);

    dim3 g4(64, 6);
    k_ogemm<<<g4, 256, 0, stream>>>(attn_bf, Wt + (size_t)3 * HH * HH, bo, proj_bf);

    k_ln<<<BB * NN, 256, 0, stream>>>(nodes, proj_bf, g_norm, b_norm, out0);
}